// Round 5
// baseline (297.115 us; speedup 1.0000x reference)
//
#include <hip/hip_runtime.h>
#include <hip/hip_bf16.h>

// AFT-Full fused pipeline, B=8, S=D=1024.  5 launches:
//   prep_all : x->bf16, weights->bf16, exp(w)->bf16, biases
//   gemm_qkv : qkv GEMM; epilogue writes q, exp(k), E=exp(k+w), v (seg-fused)
//   mid2     : pure 64x64 transpose: EKT=exp(k)^T, vT=v^T (per batch)
//   gemm_nd  : num=E@vT^T and den=exp(w)@EKT^T in one block (dual acc),
//              epilogue y = sigmoid(q)*num/den  (fp32 num/den)
//   gemm_bt  : out = y @ out_w^T + out_b   (fp32 store)

typedef float  f32x4  __attribute__((ext_vector_type(4)));
typedef short  short8 __attribute__((ext_vector_type(8)));
typedef __bf16 bf16x8 __attribute__((ext_vector_type(8)));

__device__ __forceinline__ ushort f2bf(float f){
  uint u = __builtin_bit_cast(uint, f);
  u += 0x7fffu + ((u >> 16) & 1u);          // RNE
  return (ushort)(u >> 16);
}
__device__ __forceinline__ float bf2f(ushort u){
  uint v = ((uint)u) << 16;
  return __builtin_bit_cast(float, v);
}

__device__ __forceinline__ void gload16(const ushort* g, ushort* l){
  __builtin_amdgcn_global_load_lds(
      (const __attribute__((address_space(1))) void*)g,
      (__attribute__((address_space(3))) void*)l, 16, 0, 0);
}

__device__ __forceinline__ f32x4 mfma16(short8 a, short8 b, f32x4 c){
  return __builtin_amdgcn_mfma_f32_16x16x32_bf16(
      __builtin_bit_cast(bf16x8, a), __builtin_bit_cast(bf16x8, b), c, 0, 0, 0);
}

// bijective XCD-aware slot->tile swizzle (m204); returns bx,by,bz
__device__ __forceinline__ void xcd_swz(int& bx, int& by, int& bz){
  const int nx = gridDim.x, ny = gridDim.y;
  const long nwg = (long)nx * ny * gridDim.z;
  const long lid = ((long)blockIdx.z * ny + blockIdx.y) * nx + blockIdx.x;
  const long q8 = nwg >> 3, r8 = nwg & 7;
  const long xcd = lid & 7, idx = lid >> 3;
  const long sid = (xcd < r8 ? xcd * (q8 + 1) : r8 * (q8 + 1) + (xcd - r8) * q8) + idx;
  bx = (int)(sid % nx);
  const long t1 = sid / nx;
  by = (int)(t1 % ny);
  bz = (int)(t1 / ny);
}

// ---------------------------------------------------------------------------
// gemm_qkv: [q|k|v] = x @ wcat^T + bcat, M=8192, N=3072, K=1024.
// 128x128 tile, 4 waves, BK=64, gload_lds w=16, source-side XOR pre-swizzle.
// Epilogue (block-uniform segment = tileN>>10):
//   seg0: qb = val ; seg1: kb = exp(val), Eb = exp(val + w[s][d]) ; seg2: vb.
// ---------------------------------------------------------------------------
__global__ __launch_bounds__(256) void gemm_qkv(
    const ushort* __restrict__ A, const ushort* __restrict__ B,
    const float* __restrict__ bias, const float* __restrict__ w,
    ushort* __restrict__ qb, ushort* __restrict__ kb,
    ushort* __restrict__ Eb, ushort* __restrict__ vb)
{
  __shared__ ushort As[128 * 64] __attribute__((aligned(16)));
  __shared__ ushort Bs[128 * 64] __attribute__((aligned(16)));

  int bx, by, bz; xcd_swz(bx, by, bz); (void)bz;
  const int tid  = threadIdx.x;
  const int lane = tid & 63;
  const int wid  = tid >> 6;
  const int wm   = wid >> 1;
  const int wn   = wid & 1;
  const long tileM = (long)by * 128;
  const long tileN = (long)bx * 128;
  const int  seg   = (int)(tileN >> 10);     // block-uniform (1024%128==0)

  const ushort* Ab = A + tileM * 1024;
  const ushort* Bb = B + tileN * 1024;

  long gOff[4]; int lOff[4];
#pragma unroll
  for (int j = 0; j < 4; ++j) {
    int chunk = j * 256 + tid;
    int row   = chunk >> 3;
    int c16   = (chunk & 7) ^ (row & 7);
    gOff[j]   = (long)row * 1024 + c16 * 8;
    lOff[j]   = chunk * 8;
  }

  f32x4 acc[4][4];
#pragma unroll
  for (int i = 0; i < 4; ++i)
#pragma unroll
    for (int j = 0; j < 4; ++j) acc[i][j] = (f32x4)0.f;

  const int rA0 = wm * 64 + (lane & 15);
  const int rB0 = wn * 64 + (lane & 15);
  const int cw0 = lane >> 4;

  for (int kt = 0; kt < 1024; kt += 64) {
    __syncthreads();
#pragma unroll
    for (int j = 0; j < 4; ++j) {
      gload16(Ab + gOff[j] + kt, &As[lOff[j]]);
      gload16(Bb + gOff[j] + kt, &Bs[lOff[j]]);
    }
    __syncthreads();

    short8 af[4][2], bf[4][2];
#pragma unroll
    for (int f = 0; f < 4; ++f) {
      int ra = rA0 + f * 16;
      int rb = rB0 + f * 16;
#pragma unroll
      for (int kk = 0; kk < 2; ++kk) {
        af[f][kk] = *(const short8*)&As[ra * 64 + (((kk * 4 + cw0) ^ (ra & 7)) * 8)];
        bf[f][kk] = *(const short8*)&Bs[rb * 64 + (((kk * 4 + cw0) ^ (rb & 7)) * 8)];
      }
    }
#pragma unroll
    for (int kk = 0; kk < 2; ++kk)
#pragma unroll
      for (int fi = 0; fi < 4; ++fi)
#pragma unroll
        for (int fj = 0; fj < 4; ++fj)
          acc[fi][fj] = mfma16(af[fi][kk], bf[fj][kk], acc[fi][fj]);
  }

#pragma unroll
  for (int fi = 0; fi < 4; ++fi) {
    long gm0 = tileM + wm * 64 + fi * 16 + (lane >> 4) * 4;
#pragma unroll
    for (int fj = 0; fj < 4; ++fj) {
      long gn = tileN + wn * 64 + fj * 16 + (lane & 15);
      int  nl = (int)(gn & 1023);
      float bv = bias[gn];
#pragma unroll
      for (int r = 0; r < 4; ++r) {
        long m = gm0 + r;
        float val = acc[fi][fj][r] + bv;
        long o = m * 1024 + nl;
        if (seg == 0) {
          qb[o] = f2bf(val);
        } else if (seg == 1) {
          float wv = w[(long)(m & 1023) * 1024 + nl];
          kb[o] = f2bf(expf(val));
          Eb[o] = f2bf(expf(val + wv));
        } else {
          vb[o] = f2bf(val);
        }
      }
    }
  }
}

// ---------------------------------------------------------------------------
// gemm_nd: per block (bx,by,z): dual GEMM over K=1024
//   accN = E[z]  @ vT[z]^T   (num)
//   accD = ewb   @ EKT[z]^T  (den)
// epilogue: y = sigmoid(q) * accN / accD  (fp32 num/den, bf16 store)
// ---------------------------------------------------------------------------
__global__ __launch_bounds__(256, 2) void gemm_nd(
    const ushort* __restrict__ E,  const ushort* __restrict__ vT,
    const ushort* __restrict__ ew, const ushort* __restrict__ EKT,
    const ushort* __restrict__ qb, ushort* __restrict__ y)
{
  __shared__ ushort sh[4 * 8192] __attribute__((aligned(16)));   // 64 KiB

  const long MB = 1048576;
  int bx, by, bz; xcd_swz(bx, by, bz);
  const int tid  = threadIdx.x;
  const int lane = tid & 63;
  const int wid  = tid >> 6;
  const int wm   = wid >> 1;
  const int wn   = wid & 1;
  const long tileM = (long)by * 128;
  const long tileN = (long)bx * 128;
  const long z = bz;

  const ushort* Ae = E   + z * MB + tileM * 1024;
  const ushort* Bv = vT  + z * MB + tileN * 1024;
  const ushort* Aw = ew  +          tileM * 1024;
  const ushort* Bk = EKT + z * MB + tileN * 1024;

  long gOff[4]; int lOff[4];
#pragma unroll
  for (int j = 0; j < 4; ++j) {
    int chunk = j * 256 + tid;
    int row   = chunk >> 3;
    int c16   = (chunk & 7) ^ (row & 7);
    gOff[j]   = (long)row * 1024 + c16 * 8;
    lOff[j]   = chunk * 8;
  }

  f32x4 accN[4][4], accD[4][4];
#pragma unroll
  for (int i = 0; i < 4; ++i)
#pragma unroll
    for (int j = 0; j < 4; ++j) { accN[i][j] = (f32x4)0.f; accD[i][j] = (f32x4)0.f; }

  const int rA0 = wm * 64 + (lane & 15);
  const int rB0 = wn * 64 + (lane & 15);
  const int cw0 = lane >> 4;

  for (int kt = 0; kt < 1024; kt += 64) {
    __syncthreads();
#pragma unroll
    for (int j = 0; j < 4; ++j) {
      gload16(Ae + gOff[j] + kt, &sh[lOff[j]]);
      gload16(Bv + gOff[j] + kt, &sh[8192  + lOff[j]]);
      gload16(Aw + gOff[j] + kt, &sh[16384 + lOff[j]]);
      gload16(Bk + gOff[j] + kt, &sh[24576 + lOff[j]]);
    }
    __syncthreads();

#pragma unroll
    for (int kk = 0; kk < 2; ++kk) {
      short8 a[4], b[4];
#pragma unroll
      for (int f = 0; f < 4; ++f) {
        int ra = rA0 + f * 16, rb = rB0 + f * 16;
        a[f] = *(const short8*)&sh[ra * 64 + (((kk * 4 + cw0) ^ (ra & 7)) * 8)];
        b[f] = *(const short8*)&sh[8192 + rb * 64 + (((kk * 4 + cw0) ^ (rb & 7)) * 8)];
      }
#pragma unroll
      for (int fi = 0; fi < 4; ++fi)
#pragma unroll
        for (int fj = 0; fj < 4; ++fj)
          accN[fi][fj] = mfma16(a[fi], b[fj], accN[fi][fj]);
#pragma unroll
      for (int f = 0; f < 4; ++f) {
        int ra = rA0 + f * 16, rb = rB0 + f * 16;
        a[f] = *(const short8*)&sh[16384 + ra * 64 + (((kk * 4 + cw0) ^ (ra & 7)) * 8)];
        b[f] = *(const short8*)&sh[24576 + rb * 64 + (((kk * 4 + cw0) ^ (rb & 7)) * 8)];
      }
#pragma unroll
      for (int fi = 0; fi < 4; ++fi)
#pragma unroll
        for (int fj = 0; fj < 4; ++fj)
          accD[fi][fj] = mfma16(a[fi], b[fj], accD[fi][fj]);
    }
  }

#pragma unroll
  for (int fi = 0; fi < 4; ++fi) {
    long gm0 = tileM + wm * 64 + fi * 16 + (lane >> 4) * 4;
#pragma unroll
    for (int fj = 0; fj < 4; ++fj) {
      long gn = tileN + wn * 64 + fj * 16 + (lane & 15);
#pragma unroll
      for (int r = 0; r < 4; ++r) {
        long idx = z * MB + (gm0 + r) * 1024 + gn;
        float qv = bf2f(qb[idx]);
        float s  = 1.f / (1.f + expf(-qv));
        y[idx] = f2bf(s * accN[fi][fj][r] / accD[fi][fj][r]);
      }
    }
  }
}

// ---------------------------------------------------------------------------
// 128^2 BT GEMM (m97 structure) for the out-projection (fp32 store).
// ---------------------------------------------------------------------------
__global__ __launch_bounds__(256) void gemm_out(
    const ushort* __restrict__ A, const ushort* __restrict__ B,
    float* __restrict__ C, const float* __restrict__ bias)
{
  __shared__ ushort As[128 * 64] __attribute__((aligned(16)));
  __shared__ ushort Bs[128 * 64] __attribute__((aligned(16)));

  int bx, by, bz; xcd_swz(bx, by, bz); (void)bz;
  const int tid  = threadIdx.x;
  const int lane = tid & 63;
  const int wid  = tid >> 6;
  const int wm   = wid >> 1;
  const int wn   = wid & 1;
  const long tileM = (long)by * 128;
  const long tileN = (long)bx * 128;

  const ushort* Ab = A + tileM * 1024;
  const ushort* Bb = B + tileN * 1024;

  long gOff[4]; int lOff[4];
#pragma unroll
  for (int j = 0; j < 4; ++j) {
    int chunk = j * 256 + tid;
    int row   = chunk >> 3;
    int c16   = (chunk & 7) ^ (row & 7);
    gOff[j]   = (long)row * 1024 + c16 * 8;
    lOff[j]   = chunk * 8;
  }

  f32x4 acc[4][4];
#pragma unroll
  for (int i = 0; i < 4; ++i)
#pragma unroll
    for (int j = 0; j < 4; ++j) acc[i][j] = (f32x4)0.f;

  const int rA0 = wm * 64 + (lane & 15);
  const int rB0 = wn * 64 + (lane & 15);
  const int cw0 = lane >> 4;

  for (int kt = 0; kt < 1024; kt += 64) {
    __syncthreads();
#pragma unroll
    for (int j = 0; j < 4; ++j) {
      gload16(Ab + gOff[j] + kt, &As[lOff[j]]);
      gload16(Bb + gOff[j] + kt, &Bs[lOff[j]]);
    }
    __syncthreads();

    short8 af[4][2], bf[4][2];
#pragma unroll
    for (int f = 0; f < 4; ++f) {
      int ra = rA0 + f * 16;
      int rb = rB0 + f * 16;
#pragma unroll
      for (int kk = 0; kk < 2; ++kk) {
        af[f][kk] = *(const short8*)&As[ra * 64 + (((kk * 4 + cw0) ^ (ra & 7)) * 8)];
        bf[f][kk] = *(const short8*)&Bs[rb * 64 + (((kk * 4 + cw0) ^ (rb & 7)) * 8)];
      }
    }
#pragma unroll
    for (int kk = 0; kk < 2; ++kk)
#pragma unroll
      for (int fi = 0; fi < 4; ++fi)
#pragma unroll
        for (int fj = 0; fj < 4; ++fj)
          acc[fi][fj] = mfma16(af[fi][kk], bf[fj][kk], acc[fi][fj]);
  }

#pragma unroll
  for (int fi = 0; fi < 4; ++fi) {
    long gm0 = tileM + wm * 64 + fi * 16 + (lane >> 4) * 4;
#pragma unroll
    for (int fj = 0; fj < 4; ++fj) {
      long gn = tileN + wn * 64 + fj * 16 + (lane & 15);
      float bv = bias[gn];
#pragma unroll
      for (int r = 0; r < 4; ++r)
        C[(gm0 + r) * 1024 + gn] = acc[fi][fj][r] + bv;
    }
  }
}

// ---------------------------------------------------------------------------
// prep_all: x->bf16, [wq|wk|wv]->bf16, out_w->bf16, exp(w)->bf16, biases.
// ---------------------------------------------------------------------------
__global__ void prep_all(const float* __restrict__ x,
                         const float* __restrict__ wq, const float* __restrict__ wk,
                         const float* __restrict__ wv, const float* __restrict__ ow,
                         const float* __restrict__ w,
                         const float* __restrict__ bq, const float* __restrict__ bk,
                         const float* __restrict__ bv,
                         ushort* __restrict__ xb,
                         ushort* __restrict__ wcat, ushort* __restrict__ owb,
                         ushort* __restrict__ ewb, float* __restrict__ bcat)
{
  const long MB = 1048576;
  long i4 = ((long)blockIdx.x * 256 + threadIdx.x) * 4;
  if (i4 < 8 * MB) {
    float4 v = *(const float4*)&x[i4];
    ushort4 o; o.x=f2bf(v.x); o.y=f2bf(v.y); o.z=f2bf(v.z); o.w=f2bf(v.w);
    *(ushort4*)&xb[i4] = o;
    return;
  }
  long j4 = i4 - 8 * MB;
  if (j4 < 3 * MB) {
    const float* src = (j4 < MB) ? wq : (j4 < 2 * MB ? wk : wv);
    long off = j4 & (MB - 1);
    float4 v = *(const float4*)&src[off];
    ushort4 o; o.x=f2bf(v.x); o.y=f2bf(v.y); o.z=f2bf(v.z); o.w=f2bf(v.w);
    *(ushort4*)&wcat[j4] = o;
  } else if (j4 < 4 * MB) {
    long off = j4 - 3 * MB;
    float4 v = *(const float4*)&ow[off];
    ushort4 o; o.x=f2bf(v.x); o.y=f2bf(v.y); o.z=f2bf(v.z); o.w=f2bf(v.w);
    *(ushort4*)&owb[off] = o;
  } else if (j4 < 5 * MB) {
    long off = j4 - 4 * MB;
    float4 v = *(const float4*)&w[off];
    ushort4 o;
    o.x=f2bf(expf(v.x)); o.y=f2bf(expf(v.y)); o.z=f2bf(expf(v.z)); o.w=f2bf(expf(v.w));
    *(ushort4*)&ewb[off] = o;
  } else {
    long i = j4 - 5 * MB;
    if (i < 3072) {
      const float* src = (i < 1024) ? bq : (i < 2048 ? bk : bv);
      long off = i & 1023;
      *(float4*)&bcat[i] = *(const float4*)&src[off];
    }
  }
}

// ---------------------------------------------------------------------------
// mid2: pure 64x64 transpose (per batch): EKT = kb^T (kb holds exp(k)),
// vT = vb^T.  ushort4 loads and stores (8B/lane both directions).
// ---------------------------------------------------------------------------
__global__ void mid2(const ushort* __restrict__ kb, const ushort* __restrict__ vb,
                     ushort* __restrict__ EKT, ushort* __restrict__ vT)
{
  __shared__ ushort t1[64][68];
  __shared__ ushort t2[64][68];
  const int b  = blockIdx.z;
  const int s0 = blockIdx.y * 64, d0 = blockIdx.x * 64;
  const int t  = threadIdx.x;            // 256
  const int sl = t >> 4, q4 = (t & 15) * 4;
  const long base = (long)b * 1048576;
#pragma unroll
  for (int i = 0; i < 4; ++i) {
    int s = sl + i * 16;
    long src = base + (long)(s0 + s) * 1024 + d0 + q4;
    *(ushort4*)&t1[s][q4] = *(const ushort4*)&kb[src];
    *(ushort4*)&t2[s][q4] = *(const ushort4*)&vb[src];
  }
  __syncthreads();
#pragma unroll
  for (int i = 0; i < 4; ++i) {
    int d = sl + i * 16;
    long dst = base + (long)(d0 + d) * 1024 + s0 + q4;
    ushort4 o1, o2;
    o1.x = t1[q4    ][d]; o1.y = t1[q4 + 1][d]; o1.z = t1[q4 + 2][d]; o1.w = t1[q4 + 3][d];
    o2.x = t2[q4    ][d]; o2.y = t2[q4 + 1][d]; o2.z = t2[q4 + 2][d]; o2.w = t2[q4 + 3][d];
    *(ushort4*)&EKT[dst] = o1;
    *(ushort4*)&vT [dst] = o2;
  }
}

// ---------------------------------------------------------------------------
extern "C" void kernel_launch(void* const* d_in, const int* in_sizes, int n_in,
                              void* d_out, int out_size, void* d_ws, size_t ws_size,
                              hipStream_t stream)
{
  const float* x     = (const float*)d_in[0];
  const float* wq_w  = (const float*)d_in[1];
  const float* wq_b  = (const float*)d_in[2];
  const float* wk_w  = (const float*)d_in[3];
  const float* wk_b  = (const float*)d_in[4];
  const float* wv_w  = (const float*)d_in[5];
  const float* wv_b  = (const float*)d_in[6];
  const float* w     = (const float*)d_in[7];
  const float* out_w = (const float*)d_in[8];
  const float* out_b = (const float*)d_in[9];
  float* out = (float*)d_out;

  const long MB = 1048576;
  char* ws = (char*)d_ws;
  size_t o = 0;
  auto alloc = [&](size_t bytes){ size_t r = o; o += (bytes + 255) & ~(size_t)255; return r; };

  ushort* xb   = (ushort*)(ws + alloc(8 * MB * 2));        // x bf16
  ushort* wcat = (ushort*)(ws + alloc(3 * MB * 2));        // [wq|wk|wv] bf16
  ushort* owb  = (ushort*)(ws + alloc(1 * MB * 2));        // out_w bf16
  ushort* ewb  = (ushort*)(ws + alloc(1 * MB * 2));        // exp(w) bf16
  float*  bcat = (float*) (ws + alloc(3072 * 4));          // [bq|bk|bv]
  ushort* qb   = (ushort*)(ws + alloc(8 * MB * 2));        // q
  ushort* kb   = (ushort*)(ws + alloc(8 * MB * 2));        // exp(k)
  ushort* Eb   = (ushort*)(ws + alloc(8 * MB * 2));        // exp(k+w)
  ushort* vb   = (ushort*)(ws + alloc(8 * MB * 2));        // v
  ushort* vTb  = (ushort*)(ws + alloc(8 * MB * 2));        // v^T
  ushort* EKTb = (ushort*)(ws + alloc(8 * MB * 2));        // exp(k)^T
  ushort* yb   = (ushort*)(ws + alloc(8 * MB * 2));        // y
  (void)ws_size; (void)in_sizes; (void)n_in; (void)out_size;

  // 1. input conversions
  prep_all<<<13315, 256, 0, stream>>>(x, wq_w, wk_w, wv_w, out_w, w,
                                      wq_b, wk_b, wv_b,
                                      xb, wcat, owb, ewb, bcat);

  // 2. qkv GEMM, epilogue-fused q / exp(k),E / v  (1536 blocks)
  gemm_qkv<<<dim3(24, 64, 1), 256, 0, stream>>>(
      xb, wcat, bcat, w, qb, kb, Eb, vb);

  // 3. transposes: EKT = exp(k)^T, vT = v^T  (2048 blocks)
  mid2<<<dim3(16, 16, 8), 256, 0, stream>>>(kb, vb, EKTb, vTb);

  // 4. num+den dual GEMM + y epilogue (512 blocks = one full round)
  gemm_nd<<<dim3(8, 8, 8), 256, 0, stream>>>(Eb, vTb, ewb, EKTb, qb, yb);

  // 5. out = y @ out_w^T + out_b  (512 blocks, fp32 store)
  gemm_out<<<dim3(8, 64, 1), 256, 0, stream>>>(yb, owb, out, out_b);
}

// Round 6
// 257.326 us; speedup vs baseline: 1.1546x; 1.1546x over previous
//
#include <hip/hip_runtime.h>
#include <hip/hip_bf16.h>

// AFT-Full fused pipeline, B=8, S=D=1024.  5 launches:
//   prep_all : x->bf16, weights->bf16, exp(w)->bf16, biases
//   gemm_qkv : qkv GEMM; epilogue writes q, exp(k), v (seg-fused, NO w read)
//   mid2     : E = exp(k)*exp(w) (streaming) + 64x64 transposes EKT, vT
//   gemm_nd  : num=E@vT^T and den=exp(w)@EKT^T in one block (dual acc),
//              epilogue y = sigmoid(q)*num/den  (fp32 num/den)
//   gemm_out : out = y @ out_w^T + out_b   (fp32 store)

typedef float  f32x4  __attribute__((ext_vector_type(4)));
typedef short  short8 __attribute__((ext_vector_type(8)));
typedef __bf16 bf16x8 __attribute__((ext_vector_type(8)));

__device__ __forceinline__ ushort f2bf(float f){
  uint u = __builtin_bit_cast(uint, f);
  u += 0x7fffu + ((u >> 16) & 1u);          // RNE
  return (ushort)(u >> 16);
}
__device__ __forceinline__ float bf2f(ushort u){
  uint v = ((uint)u) << 16;
  return __builtin_bit_cast(float, v);
}

__device__ __forceinline__ void gload16(const ushort* g, ushort* l){
  __builtin_amdgcn_global_load_lds(
      (const __attribute__((address_space(1))) void*)g,
      (__attribute__((address_space(3))) void*)l, 16, 0, 0);
}

__device__ __forceinline__ f32x4 mfma16(short8 a, short8 b, f32x4 c){
  return __builtin_amdgcn_mfma_f32_16x16x32_bf16(
      __builtin_bit_cast(bf16x8, a), __builtin_bit_cast(bf16x8, b), c, 0, 0, 0);
}

// bijective XCD-aware slot->tile swizzle (m204); returns bx,by,bz
__device__ __forceinline__ void xcd_swz(int& bx, int& by, int& bz){
  const int nx = gridDim.x, ny = gridDim.y;
  const long nwg = (long)nx * ny * gridDim.z;
  const long lid = ((long)blockIdx.z * ny + blockIdx.y) * nx + blockIdx.x;
  const long q8 = nwg >> 3, r8 = nwg & 7;
  const long xcd = lid & 7, idx = lid >> 3;
  const long sid = (xcd < r8 ? xcd * (q8 + 1) : r8 * (q8 + 1) + (xcd - r8) * q8) + idx;
  bx = (int)(sid % nx);
  const long t1 = sid / nx;
  by = (int)(t1 % ny);
  bz = (int)(t1 / ny);
}

// ---------------------------------------------------------------------------
// gemm_qkv: [q|k|v] = x @ wcat^T + bcat, M=8192, N=3072, K=1024.
// 128x128 tile, 4 waves, BK=64, gload_lds w=16, source-side XOR pre-swizzle.
// Epilogue (block-uniform segment = tileN>>10):
//   seg0: qb = val ; seg1: kb = exp(val) ; seg2: vb = val.
// NO broadcast-table reads in the epilogue (round-5 lesson: +86MB FETCH).
// ---------------------------------------------------------------------------
__global__ __launch_bounds__(256) void gemm_qkv(
    const ushort* __restrict__ A, const ushort* __restrict__ B,
    const float* __restrict__ bias,
    ushort* __restrict__ qb, ushort* __restrict__ kb, ushort* __restrict__ vb)
{
  __shared__ ushort As[128 * 64] __attribute__((aligned(16)));
  __shared__ ushort Bs[128 * 64] __attribute__((aligned(16)));

  int bx, by, bz; xcd_swz(bx, by, bz); (void)bz;
  const int tid  = threadIdx.x;
  const int lane = tid & 63;
  const int wid  = tid >> 6;
  const int wm   = wid >> 1;
  const int wn   = wid & 1;
  const long tileM = (long)by * 128;
  const long tileN = (long)bx * 128;
  const int  seg   = (int)(tileN >> 10);     // block-uniform (1024%128==0)

  const ushort* Ab = A + tileM * 1024;
  const ushort* Bb = B + tileN * 1024;

  long gOff[4]; int lOff[4];
#pragma unroll
  for (int j = 0; j < 4; ++j) {
    int chunk = j * 256 + tid;
    int row   = chunk >> 3;
    int c16   = (chunk & 7) ^ (row & 7);
    gOff[j]   = (long)row * 1024 + c16 * 8;
    lOff[j]   = chunk * 8;
  }

  f32x4 acc[4][4];
#pragma unroll
  for (int i = 0; i < 4; ++i)
#pragma unroll
    for (int j = 0; j < 4; ++j) acc[i][j] = (f32x4)0.f;

  const int rA0 = wm * 64 + (lane & 15);
  const int rB0 = wn * 64 + (lane & 15);
  const int cw0 = lane >> 4;

  for (int kt = 0; kt < 1024; kt += 64) {
    __syncthreads();
#pragma unroll
    for (int j = 0; j < 4; ++j) {
      gload16(Ab + gOff[j] + kt, &As[lOff[j]]);
      gload16(Bb + gOff[j] + kt, &Bs[lOff[j]]);
    }
    __syncthreads();

    short8 af[4][2], bf[4][2];
#pragma unroll
    for (int f = 0; f < 4; ++f) {
      int ra = rA0 + f * 16;
      int rb = rB0 + f * 16;
#pragma unroll
      for (int kk = 0; kk < 2; ++kk) {
        af[f][kk] = *(const short8*)&As[ra * 64 + (((kk * 4 + cw0) ^ (ra & 7)) * 8)];
        bf[f][kk] = *(const short8*)&Bs[rb * 64 + (((kk * 4 + cw0) ^ (rb & 7)) * 8)];
      }
    }
#pragma unroll
    for (int kk = 0; kk < 2; ++kk)
#pragma unroll
      for (int fi = 0; fi < 4; ++fi)
#pragma unroll
        for (int fj = 0; fj < 4; ++fj)
          acc[fi][fj] = mfma16(af[fi][kk], bf[fj][kk], acc[fi][fj]);
  }

#pragma unroll
  for (int fi = 0; fi < 4; ++fi) {
    long gm0 = tileM + wm * 64 + fi * 16 + (lane >> 4) * 4;
#pragma unroll
    for (int fj = 0; fj < 4; ++fj) {
      long gn = tileN + wn * 64 + fj * 16 + (lane & 15);
      int  nl = (int)(gn & 1023);
      float bv = bias[gn];
#pragma unroll
      for (int r = 0; r < 4; ++r) {
        long m = gm0 + r;
        float val = acc[fi][fj][r] + bv;
        long o = m * 1024 + nl;
        if (seg == 0)      qb[o] = f2bf(val);
        else if (seg == 1) kb[o] = f2bf(expf(val));
        else               vb[o] = f2bf(val);
      }
    }
  }
}

// ---------------------------------------------------------------------------
// gemm_nd: per block (bx,by,z): dual GEMM over K=1024
//   accN = E[z]  @ vT[z]^T   (num)
//   accD = ewb   @ EKT[z]^T  (den)
// epilogue: y = sigmoid(q) * accN / accD  (fp32 num/den, bf16 store)
// ---------------------------------------------------------------------------
__global__ __launch_bounds__(256, 2) void gemm_nd(
    const ushort* __restrict__ E,  const ushort* __restrict__ vT,
    const ushort* __restrict__ ew, const ushort* __restrict__ EKT,
    const ushort* __restrict__ qb, ushort* __restrict__ y)
{
  __shared__ ushort sh[4 * 8192] __attribute__((aligned(16)));   // 64 KiB

  const long MB = 1048576;
  int bx, by, bz; xcd_swz(bx, by, bz);
  const int tid  = threadIdx.x;
  const int lane = tid & 63;
  const int wid  = tid >> 6;
  const int wm   = wid >> 1;
  const int wn   = wid & 1;
  const long tileM = (long)by * 128;
  const long tileN = (long)bx * 128;
  const long z = bz;

  const ushort* Ae = E   + z * MB + tileM * 1024;
  const ushort* Bv = vT  + z * MB + tileN * 1024;
  const ushort* Aw = ew  +          tileM * 1024;
  const ushort* Bk = EKT + z * MB + tileN * 1024;

  long gOff[4]; int lOff[4];
#pragma unroll
  for (int j = 0; j < 4; ++j) {
    int chunk = j * 256 + tid;
    int row   = chunk >> 3;
    int c16   = (chunk & 7) ^ (row & 7);
    gOff[j]   = (long)row * 1024 + c16 * 8;
    lOff[j]   = chunk * 8;
  }

  f32x4 accN[4][4], accD[4][4];
#pragma unroll
  for (int i = 0; i < 4; ++i)
#pragma unroll
    for (int j = 0; j < 4; ++j) { accN[i][j] = (f32x4)0.f; accD[i][j] = (f32x4)0.f; }

  const int rA0 = wm * 64 + (lane & 15);
  const int rB0 = wn * 64 + (lane & 15);
  const int cw0 = lane >> 4;

  for (int kt = 0; kt < 1024; kt += 64) {
    __syncthreads();
#pragma unroll
    for (int j = 0; j < 4; ++j) {
      gload16(Ae + gOff[j] + kt, &sh[lOff[j]]);
      gload16(Bv + gOff[j] + kt, &sh[8192  + lOff[j]]);
      gload16(Aw + gOff[j] + kt, &sh[16384 + lOff[j]]);
      gload16(Bk + gOff[j] + kt, &sh[24576 + lOff[j]]);
    }
    __syncthreads();

#pragma unroll
    for (int kk = 0; kk < 2; ++kk) {
      short8 a[4], b[4];
#pragma unroll
      for (int f = 0; f < 4; ++f) {
        int ra = rA0 + f * 16, rb = rB0 + f * 16;
        a[f] = *(const short8*)&sh[ra * 64 + (((kk * 4 + cw0) ^ (ra & 7)) * 8)];
        b[f] = *(const short8*)&sh[8192 + rb * 64 + (((kk * 4 + cw0) ^ (rb & 7)) * 8)];
      }
#pragma unroll
      for (int fi = 0; fi < 4; ++fi)
#pragma unroll
        for (int fj = 0; fj < 4; ++fj)
          accN[fi][fj] = mfma16(a[fi], b[fj], accN[fi][fj]);
#pragma unroll
      for (int f = 0; f < 4; ++f) {
        int ra = rA0 + f * 16, rb = rB0 + f * 16;
        a[f] = *(const short8*)&sh[16384 + ra * 64 + (((kk * 4 + cw0) ^ (ra & 7)) * 8)];
        b[f] = *(const short8*)&sh[24576 + rb * 64 + (((kk * 4 + cw0) ^ (rb & 7)) * 8)];
      }
#pragma unroll
      for (int fi = 0; fi < 4; ++fi)
#pragma unroll
        for (int fj = 0; fj < 4; ++fj)
          accD[fi][fj] = mfma16(a[fi], b[fj], accD[fi][fj]);
    }
  }

#pragma unroll
  for (int fi = 0; fi < 4; ++fi) {
    long gm0 = tileM + wm * 64 + fi * 16 + (lane >> 4) * 4;
#pragma unroll
    for (int fj = 0; fj < 4; ++fj) {
      long gn = tileN + wn * 64 + fj * 16 + (lane & 15);
#pragma unroll
      for (int r = 0; r < 4; ++r) {
        long idx = z * MB + (gm0 + r) * 1024 + gn;
        float qv = bf2f(qb[idx]);
        float s  = 1.f / (1.f + expf(-qv));
        y[idx] = f2bf(s * accN[fi][fj][r] / accD[fi][fj][r]);
      }
    }
  }
}

// ---------------------------------------------------------------------------
// 128^2 BT GEMM (m97 structure) for the out-projection (fp32 store).
// ---------------------------------------------------------------------------
__global__ __launch_bounds__(256) void gemm_out(
    const ushort* __restrict__ A, const ushort* __restrict__ B,
    float* __restrict__ C, const float* __restrict__ bias)
{
  __shared__ ushort As[128 * 64] __attribute__((aligned(16)));
  __shared__ ushort Bs[128 * 64] __attribute__((aligned(16)));

  int bx, by, bz; xcd_swz(bx, by, bz); (void)bz;
  const int tid  = threadIdx.x;
  const int lane = tid & 63;
  const int wid  = tid >> 6;
  const int wm   = wid >> 1;
  const int wn   = wid & 1;
  const long tileM = (long)by * 128;
  const long tileN = (long)bx * 128;

  const ushort* Ab = A + tileM * 1024;
  const ushort* Bb = B + tileN * 1024;

  long gOff[4]; int lOff[4];
#pragma unroll
  for (int j = 0; j < 4; ++j) {
    int chunk = j * 256 + tid;
    int row   = chunk >> 3;
    int c16   = (chunk & 7) ^ (row & 7);
    gOff[j]   = (long)row * 1024 + c16 * 8;
    lOff[j]   = chunk * 8;
  }

  f32x4 acc[4][4];
#pragma unroll
  for (int i = 0; i < 4; ++i)
#pragma unroll
    for (int j = 0; j < 4; ++j) acc[i][j] = (f32x4)0.f;

  const int rA0 = wm * 64 + (lane & 15);
  const int rB0 = wn * 64 + (lane & 15);
  const int cw0 = lane >> 4;

  for (int kt = 0; kt < 1024; kt += 64) {
    __syncthreads();
#pragma unroll
    for (int j = 0; j < 4; ++j) {
      gload16(Ab + gOff[j] + kt, &As[lOff[j]]);
      gload16(Bb + gOff[j] + kt, &Bs[lOff[j]]);
    }
    __syncthreads();

    short8 af[4][2], bf[4][2];
#pragma unroll
    for (int f = 0; f < 4; ++f) {
      int ra = rA0 + f * 16;
      int rb = rB0 + f * 16;
#pragma unroll
      for (int kk = 0; kk < 2; ++kk) {
        af[f][kk] = *(const short8*)&As[ra * 64 + (((kk * 4 + cw0) ^ (ra & 7)) * 8)];
        bf[f][kk] = *(const short8*)&Bs[rb * 64 + (((kk * 4 + cw0) ^ (rb & 7)) * 8)];
      }
    }
#pragma unroll
    for (int kk = 0; kk < 2; ++kk)
#pragma unroll
      for (int fi = 0; fi < 4; ++fi)
#pragma unroll
        for (int fj = 0; fj < 4; ++fj)
          acc[fi][fj] = mfma16(af[fi][kk], bf[fj][kk], acc[fi][fj]);
  }

#pragma unroll
  for (int fi = 0; fi < 4; ++fi) {
    long gm0 = tileM + wm * 64 + fi * 16 + (lane >> 4) * 4;
#pragma unroll
    for (int fj = 0; fj < 4; ++fj) {
      long gn = tileN + wn * 64 + fj * 16 + (lane & 15);
      float bv = bias[gn];
#pragma unroll
      for (int r = 0; r < 4; ++r)
        C[(gm0 + r) * 1024 + gn] = acc[fi][fj][r] + bv;
    }
  }
}

// ---------------------------------------------------------------------------
// prep_all: x->bf16, [wq|wk|wv]->bf16, out_w->bf16, exp(w)->bf16, biases.
// ---------------------------------------------------------------------------
__global__ void prep_all(const float* __restrict__ x,
                         const float* __restrict__ wq, const float* __restrict__ wk,
                         const float* __restrict__ wv, const float* __restrict__ ow,
                         const float* __restrict__ w,
                         const float* __restrict__ bq, const float* __restrict__ bk,
                         const float* __restrict__ bv,
                         ushort* __restrict__ xb,
                         ushort* __restrict__ wcat, ushort* __restrict__ owb,
                         ushort* __restrict__ ewb, float* __restrict__ bcat)
{
  const long MB = 1048576;
  long i4 = ((long)blockIdx.x * 256 + threadIdx.x) * 4;
  if (i4 < 8 * MB) {
    float4 v = *(const float4*)&x[i4];
    ushort4 o; o.x=f2bf(v.x); o.y=f2bf(v.y); o.z=f2bf(v.z); o.w=f2bf(v.w);
    *(ushort4*)&xb[i4] = o;
    return;
  }
  long j4 = i4 - 8 * MB;
  if (j4 < 3 * MB) {
    const float* src = (j4 < MB) ? wq : (j4 < 2 * MB ? wk : wv);
    long off = j4 & (MB - 1);
    float4 v = *(const float4*)&src[off];
    ushort4 o; o.x=f2bf(v.x); o.y=f2bf(v.y); o.z=f2bf(v.z); o.w=f2bf(v.w);
    *(ushort4*)&wcat[j4] = o;
  } else if (j4 < 4 * MB) {
    long off = j4 - 3 * MB;
    float4 v = *(const float4*)&ow[off];
    ushort4 o; o.x=f2bf(v.x); o.y=f2bf(v.y); o.z=f2bf(v.z); o.w=f2bf(v.w);
    *(ushort4*)&owb[off] = o;
  } else if (j4 < 5 * MB) {
    long off = j4 - 4 * MB;
    float4 v = *(const float4*)&w[off];
    ushort4 o;
    o.x=f2bf(expf(v.x)); o.y=f2bf(expf(v.y)); o.z=f2bf(expf(v.z)); o.w=f2bf(expf(v.w));
    *(ushort4*)&ewb[off] = o;
  } else {
    long i = j4 - 5 * MB;
    if (i < 3072) {
      const float* src = (i < 1024) ? bq : (i < 2048 ? bk : bv);
      long off = i & 1023;
      *(float4*)&bcat[i] = *(const float4*)&src[off];
    }
  }
}

// ---------------------------------------------------------------------------
// mid2: per (b, 64x64 tile):
//   Eb = kb * ewb   (streaming, row-major; E = exp(k)*exp(w) = exp(k+w))
//   EKT = kb^T, vT = vb^T  (LDS transpose, ushort4 both sides)
// ---------------------------------------------------------------------------
__global__ void mid2(const ushort* __restrict__ kb, const ushort* __restrict__ vb,
                     const ushort* __restrict__ ew,
                     ushort* __restrict__ EKT, ushort* __restrict__ vT,
                     ushort* __restrict__ Eb)
{
  __shared__ ushort t1[64][68];
  __shared__ ushort t2[64][68];
  const int b  = blockIdx.z;
  const int s0 = blockIdx.y * 64, d0 = blockIdx.x * 64;
  const int t  = threadIdx.x;            // 256
  const int sl = t >> 4, q4 = (t & 15) * 4;
  const long base = (long)b * 1048576;
#pragma unroll
  for (int i = 0; i < 4; ++i) {
    int s = sl + i * 16;
    long src = base + (long)(s0 + s) * 1024 + d0 + q4;
    ushort4 kv = *(const ushort4*)&kb[src];
    ushort4 vv = *(const ushort4*)&vb[src];
    *(ushort4*)&t1[s][q4] = kv;
    *(ushort4*)&t2[s][q4] = vv;
    ushort4 wv = *(const ushort4*)&ew[(long)(s0 + s) * 1024 + d0 + q4];
    ushort4 e;
    e.x = f2bf(bf2f(kv.x) * bf2f(wv.x));
    e.y = f2bf(bf2f(kv.y) * bf2f(wv.y));
    e.z = f2bf(bf2f(kv.z) * bf2f(wv.z));
    e.w = f2bf(bf2f(kv.w) * bf2f(wv.w));
    *(ushort4*)&Eb[src] = e;
  }
  __syncthreads();
#pragma unroll
  for (int i = 0; i < 4; ++i) {
    int d = sl + i * 16;
    long dst = base + (long)(d0 + d) * 1024 + s0 + q4;
    ushort4 o1, o2;
    o1.x = t1[q4    ][d]; o1.y = t1[q4 + 1][d]; o1.z = t1[q4 + 2][d]; o1.w = t1[q4 + 3][d];
    o2.x = t2[q4    ][d]; o2.y = t2[q4 + 1][d]; o2.z = t2[q4 + 2][d]; o2.w = t2[q4 + 3][d];
    *(ushort4*)&EKT[dst] = o1;
    *(ushort4*)&vT [dst] = o2;
  }
}

// ---------------------------------------------------------------------------
extern "C" void kernel_launch(void* const* d_in, const int* in_sizes, int n_in,
                              void* d_out, int out_size, void* d_ws, size_t ws_size,
                              hipStream_t stream)
{
  const float* x     = (const float*)d_in[0];
  const float* wq_w  = (const float*)d_in[1];
  const float* wq_b  = (const float*)d_in[2];
  const float* wk_w  = (const float*)d_in[3];
  const float* wk_b  = (const float*)d_in[4];
  const float* wv_w  = (const float*)d_in[5];
  const float* wv_b  = (const float*)d_in[6];
  const float* w     = (const float*)d_in[7];
  const float* out_w = (const float*)d_in[8];
  const float* out_b = (const float*)d_in[9];
  float* out = (float*)d_out;

  const long MB = 1048576;
  char* ws = (char*)d_ws;
  size_t o = 0;
  auto alloc = [&](size_t bytes){ size_t r = o; o += (bytes + 255) & ~(size_t)255; return r; };

  ushort* xb   = (ushort*)(ws + alloc(8 * MB * 2));        // x bf16
  ushort* wcat = (ushort*)(ws + alloc(3 * MB * 2));        // [wq|wk|wv] bf16
  ushort* owb  = (ushort*)(ws + alloc(1 * MB * 2));        // out_w bf16
  ushort* ewb  = (ushort*)(ws + alloc(1 * MB * 2));        // exp(w) bf16
  float*  bcat = (float*) (ws + alloc(3072 * 4));          // [bq|bk|bv]
  ushort* qb   = (ushort*)(ws + alloc(8 * MB * 2));        // q
  ushort* kb   = (ushort*)(ws + alloc(8 * MB * 2));        // exp(k)
  ushort* Eb   = (ushort*)(ws + alloc(8 * MB * 2));        // exp(k+w)
  ushort* vb   = (ushort*)(ws + alloc(8 * MB * 2));        // v
  ushort* vTb  = (ushort*)(ws + alloc(8 * MB * 2));        // v^T
  ushort* EKTb = (ushort*)(ws + alloc(8 * MB * 2));        // exp(k)^T
  ushort* yb   = (ushort*)(ws + alloc(8 * MB * 2));        // y
  (void)ws_size; (void)in_sizes; (void)n_in; (void)out_size;

  // 1. input conversions
  prep_all<<<13315, 256, 0, stream>>>(x, wq_w, wk_w, wv_w, out_w, w,
                                      wq_b, wk_b, wv_b,
                                      xb, wcat, owb, ewb, bcat);

  // 2. qkv GEMM, epilogue-fused q / exp(k) / v  (1536 blocks)
  gemm_qkv<<<dim3(24, 64, 1), 256, 0, stream>>>(
      xb, wcat, bcat, qb, kb, vb);

  // 3. E = exp(k)*exp(w); EKT = exp(k)^T; vT = v^T  (2048 blocks)
  mid2<<<dim3(16, 16, 8), 256, 0, stream>>>(kb, vb, ewb, EKTb, vTb, Eb);

  // 4. num+den dual GEMM + y epilogue (512 blocks = one full round)
  gemm_nd<<<dim3(8, 8, 8), 256, 0, stream>>>(Eb, vTb, ewb, EKTb, qb, yb);

  // 5. out = y @ out_w^T + out_b  (512 blocks, fp32 store)
  gemm_out<<<dim3(8, 64, 1), 256, 0, stream>>>(yb, owb, out, out_b);
}